// Round 4
// baseline (1389.389 us; speedup 1.0000x reference)
//
#include <hip/hip_runtime.h>
#include <hip/hip_fp16.h>

// Persistent 256-block kernel (1 block/CU forced by ~149 KB LDS).
// Per block: rows 2b,2b+1 of all 64 Omega_t cached ONCE in LDS as fp16
// (values ~N(0,0.01) -> fp16 rel err 5e-4, absorbed by bf16-compare thresh).
// Per active step: done/argmax + h1[b] (W1 column cached in LDS) -> flag
// barrier -> replicated L2/L3/softmax per block (W2/W3 from L2) -> LDS mix
// A rows -> 5 Taylor matvec terms of expm(A)@v with a barrier each.
// Barriers: all-to-all monotonic epoch flags (no contended atomics, no
// reset; epoch base read at entry -> graph-replay-safe with skipped steps).

#define NBLK 256
#define NTHR 512
#define NSTEP 20
#define NTAY 5

__device__ int g_flag[NBLK * 4];  // one epoch word per block, 16 B stride

__device__ __forceinline__ float wredsum(float p) {
#pragma unroll
  for (int off = 32; off > 0; off >>= 1) p += __shfl_xor(p, off, 64);
  return p;
}

// ws (f32): h1g[256] @0 | wb0[512] @256 | wb1[512] @768 | vng[512] @1280

__global__ __launch_bounds__(NTHR) void petri_kernel(
    const float* __restrict__ vsrc, const float* __restrict__ vtgt,
    const float* __restrict__ omg,  const float* __restrict__ W1,
    const float* __restrict__ b1,   const float* __restrict__ W2,
    const float* __restrict__ b2,   const float* __restrict__ W3,
    const float* __restrict__ b3,   const float* __restrict__ gum,
    float* __restrict__ F, float* __restrict__ out) {
  __shared__ __half2 oh[64 * 512];   // 128 KB: {row2b[j], row2b+1[j]} per t
  __shared__ float A0_s[512], A1_s[512];
  __shared__ float v_loc[512], tgt_s[512], w_s[512];
  __shared__ float w1c_s[1024];      // W1 column b
  __shared__ float soft_s[64], h1_s[256], h2_s[128];
  __shared__ float redp[512];
  __shared__ float rf8[8];
  __shared__ int   ri8[8];
  __shared__ float acc2[2];
  __shared__ int   bc[2];            // [0]=epoch base, [1]=broadcast int

  const int b = blockIdx.x, tid = threadIdx.x;
  const int wv = tid >> 6, ln = tid & 63;

  float* h1g = F;
  float* wb0 = F + 256;
  float* wb1 = F + 768;
  float* vng = F + 1280;

  if (tid == 0)
    bc[0] = __hip_atomic_load(&g_flag[b * 4], __ATOMIC_RELAXED, __HIP_MEMORY_SCOPE_AGENT);

  v_loc[tid] = vsrc[tid];
  tgt_s[tid] = vtgt[tid];
  w1c_s[tid] = W1[tid * 256 + b];
  w1c_s[tid + 512] = W1[(tid + 512) * 256 + b];
  {
    const float* base0 = omg + (b << 10) + tid;  // row 2b of Omega_0, elem tid
#pragma unroll 4
    for (int t = 0; t < 64; ++t) {
      float x0 = base0[t * 262144];
      float x1 = base0[t * 262144 + 512];
      oh[t * 512 + tid] = __floats2half2_rn(x0, x1);
    }
  }
  __syncthreads();
  int ep = bc[0];

  // target argmax (wave argmax + tid0 scan), first-index tie-break
  int tgtIdx;
  {
    float v = tgt_s[tid]; int ix = tid;
#pragma unroll
    for (int off = 32; off > 0; off >>= 1) {
      float ov = __shfl_xor(v, off, 64); int oi = __shfl_xor(ix, off, 64);
      if (ov > v || (ov == v && oi < ix)) { v = ov; ix = oi; }
    }
    if (ln == 0) { rf8[wv] = v; ri8[wv] = ix; }
    __syncthreads();
    if (tid == 0) {
      float bv = rf8[0]; int bix = ri8[0];
      for (int q = 1; q < 8; ++q)
        if (rf8[q] > bv || (rf8[q] == bv && ri8[q] < bix)) { bv = rf8[q]; bix = ri8[q]; }
      bc[1] = bix;
    }
    __syncthreads();
    tgtIdx = bc[1];
    __syncthreads();
  }

#define GBAR()                                                                               \
  do {                                                                                       \
    ++ep;                                                                                    \
    __syncthreads();                                                                         \
    if (tid == 0) {                                                                          \
      __threadfence();                                                                       \
      __hip_atomic_store(&g_flag[b * 4], ep, __ATOMIC_RELAXED, __HIP_MEMORY_SCOPE_AGENT);    \
    }                                                                                        \
    if (tid < 64) {                                                                          \
      for (;;) {                                                                             \
        int m0 = __hip_atomic_load(&g_flag[tid * 4], __ATOMIC_RELAXED, __HIP_MEMORY_SCOPE_AGENT);          \
        int m1 = __hip_atomic_load(&g_flag[(tid + 64) * 4], __ATOMIC_RELAXED, __HIP_MEMORY_SCOPE_AGENT);   \
        int m2 = __hip_atomic_load(&g_flag[(tid + 128) * 4], __ATOMIC_RELAXED, __HIP_MEMORY_SCOPE_AGENT);  \
        int m3 = __hip_atomic_load(&g_flag[(tid + 192) * 4], __ATOMIC_RELAXED, __HIP_MEMORY_SCOPE_AGENT);  \
        int mn = min(min(m0, m1), min(m2, m3));                                              \
        if (__all(mn >= ep)) break;                                                          \
        __builtin_amdgcn_s_sleep(1);                                                         \
      }                                                                                      \
      __threadfence();                                                                       \
    }                                                                                        \
    __syncthreads();                                                                         \
  } while (0)

  int d = 0;

  for (int s = 0; s < NSTEP; ++s) {
    // ---- carry: v = vnew ; d |= argmax(vnew)==tgtIdx ----
    if (s > 0 && !d) {
      float nv = vng[tid];
      v_loc[tid] = nv;
      float v = nv; int ix = tid;
#pragma unroll
      for (int off = 32; off > 0; off >>= 1) {
        float ov = __shfl_xor(v, off, 64); int oi = __shfl_xor(ix, off, 64);
        if (ov > v || (ov == v && oi < ix)) { v = ov; ix = oi; }
      }
      if (ln == 0) { rf8[wv] = v; ri8[wv] = ix; }
      __syncthreads();
      if (tid == 0) {
        float bv = rf8[0]; int bix = ri8[0];
        for (int q = 1; q < 8; ++q)
          if (rf8[q] > bv || (rf8[q] == bv && ri8[q] < bix)) { bv = rf8[q]; bix = ri8[q]; }
        bc[1] = (bix == tgtIdx) ? 1 : 0;
      }
      __syncthreads();
      if (bc[1]) d = 1;
      __syncthreads();
    }

    if (d) {  // frozen: zero logits row, no barriers (uniform across blocks)
      if (b == 0 && tid < 64) out[512 + s * 64 + tid] = 0.0f;
      continue;
    }

    // ---- L1: h1[b] = relu(dot(concat(v,tgt), W1[:,b]) + b1[b]) ----
    {
      float p = fmaf(v_loc[tid], w1c_s[tid], tgt_s[tid] * w1c_s[tid + 512]);
      p = wredsum(p);
      if (ln == 0) rf8[wv] = p;
      __syncthreads();
      if (tid == 0) {
        float a = b1[b];
        for (int q = 0; q < 8; ++q) a += rf8[q];
        h1g[b] = fmaxf(a, 0.f);
      }
    }
    GBAR();

    // ---- replicated L2/L3/softmax (per block, W2/W3 from L2) ----
    if (tid < 256) h1_s[tid] = h1g[tid];
    __syncthreads();
    {
      const int o = tid & 127, q = tid >> 7;
      float a = 0.f;
      const float* w2p = W2 + (q << 6) * 128 + o;
#pragma unroll 8
      for (int i = 0; i < 64; ++i) a = fmaf(h1_s[(q << 6) + i], w2p[i * 128], a);
      redp[tid] = a;
    }
    __syncthreads();
    if (tid < 128) {
      float r = redp[tid] + redp[tid + 128] + redp[tid + 256] + redp[tid + 384] + b2[tid];
      h2_s[tid] = fmaxf(r, 0.f);
    }
    __syncthreads();
    {
      const int o = tid & 63, q = tid >> 6;
      float a = 0.f;
      const float* w3p = W3 + (q << 4) * 64 + o;
#pragma unroll
      for (int i = 0; i < 16; ++i) a = fmaf(h2_s[(q << 4) + i], w3p[i * 64], a);
      redp[tid] = a;
    }
    __syncthreads();
    if (tid < 64) {
      float a = b3[tid];
#pragma unroll
      for (int q = 0; q < 8; ++q) a += redp[tid + (q << 6)];
      float lg = a + gum[s * 64 + tid];  // TAU = 1
      float mx = lg;
#pragma unroll
      for (int off = 32; off > 0; off >>= 1) mx = fmaxf(mx, __shfl_xor(mx, off, 64));
      float e = __expf(lg - mx);
      float sm = e;
#pragma unroll
      for (int off = 32; off > 0; off >>= 1) sm += __shfl_xor(sm, off, 64);
      soft_s[tid] = e / sm;
      if (b == 0) out[512 + s * 64 + tid] = a;  // pre-gumbel logits
    }
    __syncthreads();

    // ---- mix 2 rows of A from LDS fp16 ----
    {
      float a0 = 0.f, a1 = 0.f;
#pragma unroll 8
      for (int t = 0; t < 64; ++t) {
        float2 xy = __half22float2(oh[t * 512 + tid]);
        float sv = soft_s[t];
        a0 = fmaf(sv, xy.x, a0);
        a1 = fmaf(sv, xy.y, a1);
      }
      A0_s[tid] = a0; A1_s[tid] = a1;
    }
    __syncthreads();

    // ---- w1 = A v ----
    {
      const float* Ar = (tid < 256) ? A0_s : A1_s;
      const int j = tid & 255;
      float p = fmaf(Ar[j], v_loc[j], Ar[j + 256] * v_loc[j + 256]);
      p = wredsum(p);
      if (ln == 0) rf8[wv] = p;
      __syncthreads();
      if (tid == 0) {
        float s0 = rf8[0] + rf8[1] + rf8[2] + rf8[3];
        float s1 = rf8[4] + rf8[5] + rf8[6] + rf8[7];
        acc2[0] = v_loc[(b << 1)] + s0;
        acc2[1] = v_loc[(b << 1) + 1] + s1;
        wb1[(b << 1)] = s0;
        wb1[(b << 1) + 1] = s1;
      }
    }
    GBAR();

    // ---- Taylor n = 2..5 (w_n = A w_{n-1} / n); last publishes vnew ----
    for (int n = 2; n <= NTAY; ++n) {
      const float* wsrc = ((n - 1) & 1) ? wb1 : wb0;
      w_s[tid] = wsrc[tid];
      __syncthreads();
      const float* Ar = (tid < 256) ? A0_s : A1_s;
      const int j = tid & 255;
      float p = fmaf(Ar[j], w_s[j], Ar[j + 256] * w_s[j + 256]);
      p = wredsum(p);
      if (ln == 0) rf8[wv] = p;
      __syncthreads();
      if (tid == 0) {
        const float inv = 1.0f / (float)n;
        float s0 = (rf8[0] + rf8[1] + rf8[2] + rf8[3]) * inv;
        float s1 = (rf8[4] + rf8[5] + rf8[6] + rf8[7]) * inv;
        acc2[0] += s0; acc2[1] += s1;
        if (n < NTAY) {
          float* wd = (n & 1) ? wb1 : wb0;
          wd[(b << 1)] = s0; wd[(b << 1) + 1] = s1;
        } else {
          vng[(b << 1)] = acc2[0];
          vng[(b << 1) + 1] = acc2[1];
        }
      }
      GBAR();
    }
  }

  // ---- epilogue: v_final ----
  if (b == 0) out[tid] = d ? v_loc[tid] : vng[tid];
}

extern "C" void kernel_launch(void* const* d_in, const int* in_sizes, int n_in,
                              void* d_out, int out_size, void* d_ws, size_t ws_size,
                              hipStream_t stream) {
  (void)in_sizes; (void)n_in; (void)out_size; (void)ws_size;
  petri_kernel<<<dim3(NBLK), dim3(NTHR), 0, stream>>>(
      (const float*)d_in[0], (const float*)d_in[1], (const float*)d_in[2],
      (const float*)d_in[3], (const float*)d_in[4], (const float*)d_in[5],
      (const float*)d_in[6], (const float*)d_in[7], (const float*)d_in[8],
      (const float*)d_in[9], (float*)d_ws, (float*)d_out);
}

// Round 6
// 1148.556 us; speedup vs baseline: 1.2097x; 1.2097x over previous
//
#include <hip/hip_runtime.h>
#include <hip/hip_fp16.h>

// Persistent 256-block kernel (1 block/CU forced by ~146 KB LDS).
// Rows 2b,2b+1 of all 64 Omega_t cached ONCE in LDS as fp16 (R4: validated,
// absmax 0.0078). Per active step: h1[b] -> flag barrier -> replicated
// L2/L3/softmax -> LDS mix of A rows -> 4 Taylor matvec terms of expm(A)@v
// (remainder <=1.5e-4 rel), one barrier each.
// R4 post-mortem: 19us/barrier from reader-side same-line contention
// (256 flags on 64 lines, s_sleep(1) hammering). Fix: 64 B flag stride
// (1 line/flag) + exponential backoff polling (constant-arg s_sleep ladder
// -- R5 failed to compile with a variable sleep arg). NTAY 5->4.

#define NBLK 256
#define NTHR 512
#define NSTEP 20
#define NTAY 4

__device__ int g_flag[NBLK * 16];  // one epoch word per block, 64 B stride

__device__ __forceinline__ float wredsum(float p) {
#pragma unroll
  for (int off = 32; off > 0; off >>= 1) p += __shfl_xor(p, off, 64);
  return p;
}

// ws (f32): h1g[256] @0 | wb0[512] @256 | wb1[512] @768 | vng[512] @1280

__global__ __launch_bounds__(NTHR) void petri_kernel(
    const float* __restrict__ vsrc, const float* __restrict__ vtgt,
    const float* __restrict__ omg,  const float* __restrict__ W1,
    const float* __restrict__ b1,   const float* __restrict__ W2,
    const float* __restrict__ b2,   const float* __restrict__ W3,
    const float* __restrict__ b3,   const float* __restrict__ gum,
    float* __restrict__ F, float* __restrict__ out) {
  __shared__ __half2 oh[64 * 512];   // 128 KB: {row2b[j], row2b+1[j]} per t
  __shared__ float A0_s[512], A1_s[512];
  __shared__ float v_loc[512], tgt_s[512], w_s[512];
  __shared__ float w1c_s[1024];      // W1 column b
  __shared__ float soft_s[64], h1_s[256], h2_s[128];
  __shared__ float redp[512];
  __shared__ float rf8[8];
  __shared__ int   ri8[8];
  __shared__ float acc2[2];
  __shared__ int   bc[2];            // [0]=epoch base, [1]=broadcast int

  const int b = blockIdx.x, tid = threadIdx.x;
  const int wv = tid >> 6, ln = tid & 63;

  float* h1g = F;
  float* wb0 = F + 256;
  float* wb1 = F + 768;
  float* vng = F + 1280;

  if (tid == 0)
    bc[0] = __hip_atomic_load(&g_flag[b * 16], __ATOMIC_RELAXED, __HIP_MEMORY_SCOPE_AGENT);

  v_loc[tid] = vsrc[tid];
  tgt_s[tid] = vtgt[tid];
  w1c_s[tid] = W1[tid * 256 + b];
  w1c_s[tid + 512] = W1[(tid + 512) * 256 + b];
  {
    const float* base0 = omg + (b << 10) + tid;  // row 2b of Omega_0, elem tid
#pragma unroll 4
    for (int t = 0; t < 64; ++t) {
      float x0 = base0[t * 262144];
      float x1 = base0[t * 262144 + 512];
      oh[t * 512 + tid] = __floats2half2_rn(x0, x1);
    }
  }
  __syncthreads();
  int ep = bc[0];

  // target argmax (wave argmax + tid0 scan), first-index tie-break
  int tgtIdx;
  {
    float v = tgt_s[tid]; int ix = tid;
#pragma unroll
    for (int off = 32; off > 0; off >>= 1) {
      float ov = __shfl_xor(v, off, 64); int oi = __shfl_xor(ix, off, 64);
      if (ov > v || (ov == v && oi < ix)) { v = ov; ix = oi; }
    }
    if (ln == 0) { rf8[wv] = v; ri8[wv] = ix; }
    __syncthreads();
    if (tid == 0) {
      float bv = rf8[0]; int bix = ri8[0];
      for (int q = 1; q < 8; ++q)
        if (rf8[q] > bv || (rf8[q] == bv && ri8[q] < bix)) { bv = rf8[q]; bix = ri8[q]; }
      bc[1] = bix;
    }
    __syncthreads();
    tgtIdx = bc[1];
    __syncthreads();
  }

#define GBAR()                                                                               \
  do {                                                                                       \
    ++ep;                                                                                    \
    __syncthreads();                                                                         \
    if (tid == 0) {                                                                          \
      __threadfence();                                                                       \
      __hip_atomic_store(&g_flag[b * 16], ep, __ATOMIC_RELAXED, __HIP_MEMORY_SCOPE_AGENT);   \
    }                                                                                        \
    if (tid < 64) {                                                                          \
      int it = 0;                                                                            \
      for (;;) {                                                                             \
        int m0 = __hip_atomic_load(&g_flag[tid * 16], __ATOMIC_RELAXED, __HIP_MEMORY_SCOPE_AGENT);          \
        int m1 = __hip_atomic_load(&g_flag[(tid + 64) * 16], __ATOMIC_RELAXED, __HIP_MEMORY_SCOPE_AGENT);   \
        int m2 = __hip_atomic_load(&g_flag[(tid + 128) * 16], __ATOMIC_RELAXED, __HIP_MEMORY_SCOPE_AGENT);  \
        int m3 = __hip_atomic_load(&g_flag[(tid + 192) * 16], __ATOMIC_RELAXED, __HIP_MEMORY_SCOPE_AGENT);  \
        int mn = min(min(m0, m1), min(m2, m3));                                              \
        if (__all(mn >= ep)) break;                                                          \
        if (it == 0)      __builtin_amdgcn_s_sleep(1);                                       \
        else if (it == 1) __builtin_amdgcn_s_sleep(2);                                       \
        else if (it == 2) __builtin_amdgcn_s_sleep(4);                                       \
        else if (it == 3) __builtin_amdgcn_s_sleep(8);                                       \
        else              __builtin_amdgcn_s_sleep(16);                                      \
        if (it < 4) ++it;                                                                    \
      }                                                                                      \
      __threadfence();                                                                       \
    }                                                                                        \
    __syncthreads();                                                                         \
  } while (0)

  int d = 0;

  for (int s = 0; s < NSTEP; ++s) {
    // ---- carry: v = vnew ; d |= argmax(vnew)==tgtIdx ----
    if (s > 0 && !d) {
      float nv = vng[tid];
      v_loc[tid] = nv;
      float v = nv; int ix = tid;
#pragma unroll
      for (int off = 32; off > 0; off >>= 1) {
        float ov = __shfl_xor(v, off, 64); int oi = __shfl_xor(ix, off, 64);
        if (ov > v || (ov == v && oi < ix)) { v = ov; ix = oi; }
      }
      if (ln == 0) { rf8[wv] = v; ri8[wv] = ix; }
      __syncthreads();
      if (tid == 0) {
        float bv = rf8[0]; int bix = ri8[0];
        for (int q = 1; q < 8; ++q)
          if (rf8[q] > bv || (rf8[q] == bv && ri8[q] < bix)) { bv = rf8[q]; bix = ri8[q]; }
        bc[1] = (bix == tgtIdx) ? 1 : 0;
      }
      __syncthreads();
      if (bc[1]) d = 1;
      __syncthreads();
    }

    if (d) {  // frozen: zero logits row, no barriers (uniform across blocks)
      if (b == 0 && tid < 64) out[512 + s * 64 + tid] = 0.0f;
      continue;
    }

    // ---- L1: h1[b] = relu(dot(concat(v,tgt), W1[:,b]) + b1[b]) ----
    {
      float p = fmaf(v_loc[tid], w1c_s[tid], tgt_s[tid] * w1c_s[tid + 512]);
      p = wredsum(p);
      if (ln == 0) rf8[wv] = p;
      __syncthreads();
      if (tid == 0) {
        float a = b1[b];
        for (int q = 0; q < 8; ++q) a += rf8[q];
        h1g[b] = fmaxf(a, 0.f);
      }
    }
    GBAR();

    // ---- replicated L2/L3/softmax (per block, W2/W3 from L2) ----
    if (tid < 256) h1_s[tid] = h1g[tid];
    __syncthreads();
    {
      const int o = tid & 127, q = tid >> 7;
      float a = 0.f;
      const float* w2p = W2 + (q << 6) * 128 + o;
#pragma unroll 8
      for (int i = 0; i < 64; ++i) a = fmaf(h1_s[(q << 6) + i], w2p[i * 128], a);
      redp[tid] = a;
    }
    __syncthreads();
    if (tid < 128) {
      float r = redp[tid] + redp[tid + 128] + redp[tid + 256] + redp[tid + 384] + b2[tid];
      h2_s[tid] = fmaxf(r, 0.f);
    }
    __syncthreads();
    {
      const int o = tid & 63, q = tid >> 6;
      float a = 0.f;
      const float* w3p = W3 + (q << 4) * 64 + o;
#pragma unroll
      for (int i = 0; i < 16; ++i) a = fmaf(h2_s[(q << 4) + i], w3p[i * 64], a);
      redp[tid] = a;
    }
    __syncthreads();
    if (tid < 64) {
      float a = b3[tid];
#pragma unroll
      for (int q = 0; q < 8; ++q) a += redp[tid + (q << 6)];
      float lg = a + gum[s * 64 + tid];  // TAU = 1
      float mx = lg;
#pragma unroll
      for (int off = 32; off > 0; off >>= 1) mx = fmaxf(mx, __shfl_xor(mx, off, 64));
      float e = __expf(lg - mx);
      float sm = e;
#pragma unroll
      for (int off = 32; off > 0; off >>= 1) sm += __shfl_xor(sm, off, 64);
      soft_s[tid] = e / sm;
      if (b == 0) out[512 + s * 64 + tid] = a;  // pre-gumbel logits
    }
    __syncthreads();

    // ---- mix 2 rows of A from LDS fp16 ----
    {
      float a0 = 0.f, a1 = 0.f;
#pragma unroll 8
      for (int t = 0; t < 64; ++t) {
        float2 xy = __half22float2(oh[t * 512 + tid]);
        float sv = soft_s[t];
        a0 = fmaf(sv, xy.x, a0);
        a1 = fmaf(sv, xy.y, a1);
      }
      A0_s[tid] = a0; A1_s[tid] = a1;
    }
    __syncthreads();

    // ---- w1 = A v ----
    {
      const float* Ar = (tid < 256) ? A0_s : A1_s;
      const int j = tid & 255;
      float p = fmaf(Ar[j], v_loc[j], Ar[j + 256] * v_loc[j + 256]);
      p = wredsum(p);
      if (ln == 0) rf8[wv] = p;
      __syncthreads();
      if (tid == 0) {
        float s0 = rf8[0] + rf8[1] + rf8[2] + rf8[3];
        float s1 = rf8[4] + rf8[5] + rf8[6] + rf8[7];
        acc2[0] = v_loc[(b << 1)] + s0;
        acc2[1] = v_loc[(b << 1) + 1] + s1;
        wb1[(b << 1)] = s0;
        wb1[(b << 1) + 1] = s1;
      }
    }
    GBAR();

    // ---- Taylor n = 2..NTAY (w_n = A w_{n-1} / n); last publishes vnew ----
    for (int n = 2; n <= NTAY; ++n) {
      const float* wsrc = ((n - 1) & 1) ? wb1 : wb0;
      w_s[tid] = wsrc[tid];
      __syncthreads();
      const float* Ar = (tid < 256) ? A0_s : A1_s;
      const int j = tid & 255;
      float p = fmaf(Ar[j], w_s[j], Ar[j + 256] * w_s[j + 256]);
      p = wredsum(p);
      if (ln == 0) rf8[wv] = p;
      __syncthreads();
      if (tid == 0) {
        const float inv = 1.0f / (float)n;
        float s0 = (rf8[0] + rf8[1] + rf8[2] + rf8[3]) * inv;
        float s1 = (rf8[4] + rf8[5] + rf8[6] + rf8[7]) * inv;
        acc2[0] += s0; acc2[1] += s1;
        if (n < NTAY) {
          float* wd = (n & 1) ? wb1 : wb0;
          wd[(b << 1)] = s0; wd[(b << 1) + 1] = s1;
        } else {
          vng[(b << 1)] = acc2[0];
          vng[(b << 1) + 1] = acc2[1];
        }
      }
      GBAR();
    }
  }

  // ---- epilogue: v_final ----
  if (b == 0) out[tid] = d ? v_loc[tid] : vng[tid];
}

extern "C" void kernel_launch(void* const* d_in, const int* in_sizes, int n_in,
                              void* d_out, int out_size, void* d_ws, size_t ws_size,
                              hipStream_t stream) {
  (void)in_sizes; (void)n_in; (void)out_size; (void)ws_size;
  petri_kernel<<<dim3(NBLK), dim3(NTHR), 0, stream>>>(
      (const float*)d_in[0], (const float*)d_in[1], (const float*)d_in[2],
      (const float*)d_in[3], (const float*)d_in[4], (const float*)d_in[5],
      (const float*)d_in[6], (const float*)d_in[7], (const float*)d_in[8],
      (const float*)d_in[9], (float*)d_ws, (float*)d_out);
}

// Round 7
// 516.778 us; speedup vs baseline: 2.6886x; 2.2225x over previous
//
#include <hip/hip_runtime.h>
#include <hip/hip_fp16.h>

// Persistent 256-block kernel (1 block/CU forced by ~146 KB LDS).
// Rows 2b,2b+1 of all 64 Omega_t cached ONCE in LDS as fp16 (validated R4/R6,
// absmax 0.0078). NTAY=4 Taylor terms of expm(A)@v.
//
// R6 post-mortem: ~19 us per grid barrier, insensitive to flag stride and
// poll backoff -> cost is the __threadfence() pair (agent release/acquire =>
// L2 writeback + invalidate on multi-XCD gfx950), not reader contention.
// R7: NO fences, NO barriers. All cross-block exchange is tagged-payload
// dataflow: each 8-byte word = (float payload << 32) | round_tag, moved with
// relaxed agent-scope 64-bit atomics (coherent-point access, no fence
// needed; tag+payload in one atom, no ordering needed). 5 rounds per active
// step: h1(256 words), w1, w2, w3, vnew (512 words each), in 8 rotating
// buffers in d_ws (re-poisoned 0xAA each launch -> tags r+1 never collide;
// dataflow lockstep bounds skew to +-1 round, reuse distance 8 is safe).

#define NBLK 256
#define NTHR 512
#define NSTEP 20
#define NTAY 4
#define RBUF 8

typedef unsigned long long ull;

__device__ __forceinline__ float wredsum(float p) {
#pragma unroll
  for (int off = 32; off > 0; off >>= 1) p += __shfl_xor(p, off, 64);
  return p;
}

__device__ __forceinline__ void publish(ull* w, float v, unsigned int tag) {
  ull x = ((ull)__float_as_uint(v) << 32) | (ull)tag;
  __hip_atomic_store(w, x, __ATOMIC_RELAXED, __HIP_MEMORY_SCOPE_AGENT);
}

__device__ __forceinline__ float poll_word(ull* w, unsigned int tag) {
  int it = 0;
  for (;;) {
    ull x = __hip_atomic_load(w, __ATOMIC_RELAXED, __HIP_MEMORY_SCOPE_AGENT);
    if ((unsigned int)x == tag) return __uint_as_float((unsigned int)(x >> 32));
    if (it == 0)      __builtin_amdgcn_s_sleep(1);
    else if (it == 1) __builtin_amdgcn_s_sleep(2);
    else if (it == 2) __builtin_amdgcn_s_sleep(4);
    else              __builtin_amdgcn_s_sleep(8);
    if (it < 3) ++it;
  }
}

__global__ __launch_bounds__(NTHR) void petri_kernel(
    const float* __restrict__ vsrc, const float* __restrict__ vtgt,
    const float* __restrict__ omg,  const float* __restrict__ W1,
    const float* __restrict__ b1,   const float* __restrict__ W2,
    const float* __restrict__ b2,   const float* __restrict__ W3,
    const float* __restrict__ b3,   const float* __restrict__ gum,
    ull* __restrict__ X, float* __restrict__ out) {
  __shared__ __half2 oh[64 * 512];   // 128 KB: {row2b[j], row2b+1[j]} per t
  __shared__ float A0_s[512], A1_s[512];
  __shared__ float v_loc[512], tgt_s[512], w_s[512];
  __shared__ float w1c_s[1024];      // W1 column b (both halves)
  __shared__ float soft_s[64], h1_s[256], h2_s[128];
  __shared__ float redp[512];
  __shared__ float rf8[8];
  __shared__ int   ri8[8];
  __shared__ float acc2[2];
  __shared__ int   bc[1];

  const int b = blockIdx.x, tid = threadIdx.x;
  const int wv = tid >> 6, ln = tid & 63;

  v_loc[tid] = vsrc[tid];
  tgt_s[tid] = vtgt[tid];
  w1c_s[tid] = W1[tid * 256 + b];
  w1c_s[tid + 512] = W1[(tid + 512) * 256 + b];
  {
    const float* base0 = omg + (b << 10) + tid;  // row 2b of Omega_0, elem tid
#pragma unroll 4
    for (int t = 0; t < 64; ++t) {
      float x0 = base0[t * 262144];
      float x1 = base0[t * 262144 + 512];
      oh[t * 512 + tid] = __floats2half2_rn(x0, x1);
    }
  }
  __syncthreads();

  // target argmax (identical in every block), first-index tie-break
  int tgtIdx;
  {
    float v = tgt_s[tid]; int ix = tid;
#pragma unroll
    for (int off = 32; off > 0; off >>= 1) {
      float ov = __shfl_xor(v, off, 64); int oi = __shfl_xor(ix, off, 64);
      if (ov > v || (ov == v && oi < ix)) { v = ov; ix = oi; }
    }
    if (ln == 0) { rf8[wv] = v; ri8[wv] = ix; }
    __syncthreads();
    if (tid == 0) {
      float bv = rf8[0]; int bix = ri8[0];
      for (int q = 1; q < 8; ++q)
        if (rf8[q] > bv || (rf8[q] == bv && ri8[q] < bix)) { bv = rf8[q]; bix = ri8[q]; }
      bc[0] = bix;
    }
    __syncthreads();
    tgtIdx = bc[0];
    __syncthreads();
  }

  int d = 0;
  int r = 0;  // global round counter (uniform across blocks)

  for (int s = 0; s < NSTEP; ++s) {
    if (d) {  // frozen: zero logits row; no exchanges (uniform across blocks)
      if (b == 0 && tid < 64) out[512 + s * 64 + tid] = 0.0f;
      continue;
    }

    // ---- round r: h1[b] = relu(dot(concat(v,tgt), W1[:,b]) + b1[b]) ----
    {
      float p = fmaf(v_loc[tid], w1c_s[tid], tgt_s[tid] * w1c_s[tid + 512]);
      p = wredsum(p);
      if (ln == 0) rf8[wv] = p;
      __syncthreads();
      if (tid == 0) {
        float a = b1[b];
        for (int q = 0; q < 8; ++q) a += rf8[q];
        publish(&X[(r & (RBUF - 1)) * 512 + b], fmaxf(a, 0.f), (unsigned int)(r + 1));
      }
      if (tid < 256)
        h1_s[tid] = poll_word(&X[(r & (RBUF - 1)) * 512 + tid], (unsigned int)(r + 1));
      __syncthreads();
      ++r;
    }

    // ---- replicated L2/L3/softmax (identical in every block) ----
    {
      const int o = tid & 127, q = tid >> 7;
      float a = 0.f;
      const float* w2p = W2 + (q << 6) * 128 + o;
#pragma unroll 8
      for (int i = 0; i < 64; ++i) a = fmaf(h1_s[(q << 6) + i], w2p[i * 128], a);
      redp[tid] = a;
    }
    __syncthreads();
    if (tid < 128) {
      float rr = redp[tid] + redp[tid + 128] + redp[tid + 256] + redp[tid + 384] + b2[tid];
      h2_s[tid] = fmaxf(rr, 0.f);
    }
    __syncthreads();
    {
      const int o = tid & 63, q = tid >> 6;
      float a = 0.f;
      const float* w3p = W3 + (q << 4) * 64 + o;
#pragma unroll
      for (int i = 0; i < 16; ++i) a = fmaf(h2_s[(q << 4) + i], w3p[i * 64], a);
      redp[tid] = a;
    }
    __syncthreads();
    if (tid < 64) {
      float a = b3[tid];
#pragma unroll
      for (int q = 0; q < 8; ++q) a += redp[tid + (q << 6)];
      float lg = a + gum[s * 64 + tid];  // TAU = 1
      float mx = lg;
#pragma unroll
      for (int off = 32; off > 0; off >>= 1) mx = fmaxf(mx, __shfl_xor(mx, off, 64));
      float e = __expf(lg - mx);
      float sm = e;
#pragma unroll
      for (int off = 32; off > 0; off >>= 1) sm += __shfl_xor(sm, off, 64);
      soft_s[tid] = e / sm;
      if (b == 0) out[512 + s * 64 + tid] = a;  // pre-gumbel logits
    }
    __syncthreads();

    // ---- mix 2 rows of A from LDS fp16 ----
    {
      float a0 = 0.f, a1 = 0.f;
#pragma unroll 8
      for (int t = 0; t < 64; ++t) {
        float2 xy = __half22float2(oh[t * 512 + tid]);
        float sv = soft_s[t];
        a0 = fmaf(sv, xy.x, a0);
        a1 = fmaf(sv, xy.y, a1);
      }
      A0_s[tid] = a0; A1_s[tid] = a1;
    }
    __syncthreads();

    // ---- round r: w1 = A v ; publish, gather into w_s ----
    {
      const float* Ar = (tid < 256) ? A0_s : A1_s;
      const int j = tid & 255;
      float p = fmaf(Ar[j], v_loc[j], Ar[j + 256] * v_loc[j + 256]);
      p = wredsum(p);
      if (ln == 0) rf8[wv] = p;
      __syncthreads();
      if (tid == 0) {
        float s0 = rf8[0] + rf8[1] + rf8[2] + rf8[3];
        float s1 = rf8[4] + rf8[5] + rf8[6] + rf8[7];
        acc2[0] = v_loc[(b << 1)] + s0;
        acc2[1] = v_loc[(b << 1) + 1] + s1;
        publish(&X[(r & (RBUF - 1)) * 512 + (b << 1)], s0, (unsigned int)(r + 1));
        publish(&X[(r & (RBUF - 1)) * 512 + (b << 1) + 1], s1, (unsigned int)(r + 1));
      }
      w_s[tid] = poll_word(&X[(r & (RBUF - 1)) * 512 + tid], (unsigned int)(r + 1));
      __syncthreads();
      ++r;
    }

    // ---- rounds: Taylor n = 2..NTAY ; last publishes vnew, gather v_loc ----
    for (int n = 2; n <= NTAY; ++n) {
      const float* Ar = (tid < 256) ? A0_s : A1_s;
      const int j = tid & 255;
      float p = fmaf(Ar[j], w_s[j], Ar[j + 256] * w_s[j + 256]);
      p = wredsum(p);
      if (ln == 0) rf8[wv] = p;
      __syncthreads();
      if (tid == 0) {
        const float inv = 1.0f / (float)n;
        float s0 = (rf8[0] + rf8[1] + rf8[2] + rf8[3]) * inv;
        float s1 = (rf8[4] + rf8[5] + rf8[6] + rf8[7]) * inv;
        acc2[0] += s0; acc2[1] += s1;
        float p0 = (n < NTAY) ? s0 : acc2[0];
        float p1 = (n < NTAY) ? s1 : acc2[1];
        publish(&X[(r & (RBUF - 1)) * 512 + (b << 1)], p0, (unsigned int)(r + 1));
        publish(&X[(r & (RBUF - 1)) * 512 + (b << 1) + 1], p1, (unsigned int)(r + 1));
      }
      float g = poll_word(&X[(r & (RBUF - 1)) * 512 + tid], (unsigned int)(r + 1));
      if (n < NTAY) {
        w_s[tid] = g;
        __syncthreads();
        ++r;
      } else {
        // ---- vnew gathered: carry + done check (identical everywhere) ----
        v_loc[tid] = g;
        float v = g; int ix = tid;
#pragma unroll
        for (int off = 32; off > 0; off >>= 1) {
          float ov = __shfl_xor(v, off, 64); int oi = __shfl_xor(ix, off, 64);
          if (ov > v || (ov == v && oi < ix)) { v = ov; ix = oi; }
        }
        if (ln == 0) { rf8[wv] = v; ri8[wv] = ix; }
        __syncthreads();
        if (tid == 0) {
          float bv = rf8[0]; int bix = ri8[0];
          for (int q = 1; q < 8; ++q)
            if (rf8[q] > bv || (rf8[q] == bv && ri8[q] < bix)) { bv = rf8[q]; bix = ri8[q]; }
          bc[0] = (bix == tgtIdx) ? 1 : 0;
        }
        __syncthreads();
        if (bc[0]) d = 1;
        __syncthreads();
        ++r;
      }
    }
  }

  // ---- epilogue: v_loc holds v_final (frozen at done or vnew_19) ----
  if (b == 0) out[tid] = v_loc[tid];
}

extern "C" void kernel_launch(void* const* d_in, const int* in_sizes, int n_in,
                              void* d_out, int out_size, void* d_ws, size_t ws_size,
                              hipStream_t stream) {
  (void)in_sizes; (void)n_in; (void)out_size; (void)ws_size;
  petri_kernel<<<dim3(NBLK), dim3(NTHR), 0, stream>>>(
      (const float*)d_in[0], (const float*)d_in[1], (const float*)d_in[2],
      (const float*)d_in[3], (const float*)d_in[4], (const float*)d_in[5],
      (const float*)d_in[6], (const float*)d_in[7], (const float*)d_in[8],
      (const float*)d_in[9], (ull*)d_ws, (float*)d_out);
}

// Round 8
// 414.881 us; speedup vs baseline: 3.3489x; 1.2456x over previous
//
#include <hip/hip_runtime.h>
#include <hip/hip_fp16.h>

// Persistent 256-block kernel (1 block/CU forced by ~146 KB LDS).
// Rows 2b,2b+1 of all 64 Omega_t cached ONCE in LDS as fp16 (validated
// R4/R6/R7, absmax 0.0078). NTAY=3 Taylor terms of expm(A)@v
// (worst-case trunc ~1.7e-3/step, typ ~1e-5; threshold 0.087).
//
// Cross-block exchange (R7, fence-free): 8-byte word = payload<<32 | tag,
// relaxed agent-scope atomics only. R8: ONE WORD PER 64 B CACHELINE
// (R7 post-mortem: 4 KB buffer = 64 lines x 2048 pollers -> IC line
// serialization ~6 us/round; stride-64B cuts pollers/line 8x).
// 4 rotating buffers (128 KB of d_ws; lockstep induction: all blocks
// consume round r before any publishes r+2 -> distance-4 reuse safe).
// d_ws re-poisoned 0xAA each launch -> tags never collide; no device state.

#define NBLK 256
#define NTHR 512
#define NSTEP 20
#define NTAY 3
#define RBUF 4

typedef unsigned long long ull;

// word i of buffer buf lives at X + ((buf<<9)+i)*8  (64 B apart)
#define XW(buf, i) (X + ((((buf) << 9) + (i)) << 3))

__device__ __forceinline__ float wredsum(float p) {
#pragma unroll
  for (int off = 32; off > 0; off >>= 1) p += __shfl_xor(p, off, 64);
  return p;
}

__device__ __forceinline__ void publish(ull* w, float v, unsigned int tag) {
  ull x = ((ull)__float_as_uint(v) << 32) | (ull)tag;
  __hip_atomic_store(w, x, __ATOMIC_RELAXED, __HIP_MEMORY_SCOPE_AGENT);
}

__device__ __forceinline__ float poll_word(ull* w, unsigned int tag) {
  int it = 0;
  for (;;) {
    ull x = __hip_atomic_load(w, __ATOMIC_RELAXED, __HIP_MEMORY_SCOPE_AGENT);
    if ((unsigned int)x == tag) return __uint_as_float((unsigned int)(x >> 32));
    if (it < 2) __builtin_amdgcn_s_sleep(1);
    else        __builtin_amdgcn_s_sleep(2);
    if (it < 2) ++it;
  }
}

__global__ __launch_bounds__(NTHR) void petri_kernel(
    const float* __restrict__ vsrc, const float* __restrict__ vtgt,
    const float* __restrict__ omg,  const float* __restrict__ W1,
    const float* __restrict__ b1,   const float* __restrict__ W2,
    const float* __restrict__ b2,   const float* __restrict__ W3,
    const float* __restrict__ b3,   const float* __restrict__ gum,
    ull* __restrict__ X, float* __restrict__ out) {
  __shared__ __half2 oh[64 * 512];   // 128 KB: {row2b[j], row2b+1[j]} per t
  __shared__ float A0_s[512], A1_s[512];
  __shared__ float v_loc[512], tgt_s[512], w_s[512];
  __shared__ float w1c_s[1024];      // W1 column b (both halves)
  __shared__ float soft_s[64], h1_s[256], h2_s[128];
  __shared__ float redp[512];
  __shared__ float rf8[8];
  __shared__ int   ri8[8];
  __shared__ float acc2[2];
  __shared__ int   bc[1];

  const int b = blockIdx.x, tid = threadIdx.x;
  const int wv = tid >> 6, ln = tid & 63;

  v_loc[tid] = vsrc[tid];
  tgt_s[tid] = vtgt[tid];
  w1c_s[tid] = W1[tid * 256 + b];
  w1c_s[tid + 512] = W1[(tid + 512) * 256 + b];
  {
    const float* base0 = omg + (b << 10) + tid;  // row 2b of Omega_0, elem tid
#pragma unroll 4
    for (int t = 0; t < 64; ++t) {
      float x0 = base0[t * 262144];
      float x1 = base0[t * 262144 + 512];
      oh[t * 512 + tid] = __floats2half2_rn(x0, x1);
    }
  }
  __syncthreads();

  // target argmax (identical in every block), first-index tie-break
  int tgtIdx;
  {
    float v = tgt_s[tid]; int ix = tid;
#pragma unroll
    for (int off = 32; off > 0; off >>= 1) {
      float ov = __shfl_xor(v, off, 64); int oi = __shfl_xor(ix, off, 64);
      if (ov > v || (ov == v && oi < ix)) { v = ov; ix = oi; }
    }
    if (ln == 0) { rf8[wv] = v; ri8[wv] = ix; }
    __syncthreads();
    if (tid == 0) {
      float bv = rf8[0]; int bix = ri8[0];
      for (int q = 1; q < 8; ++q)
        if (rf8[q] > bv || (rf8[q] == bv && ri8[q] < bix)) { bv = rf8[q]; bix = ri8[q]; }
      bc[0] = bix;
    }
    __syncthreads();
    tgtIdx = bc[0];
    __syncthreads();
  }

  int d = 0;
  int r = 0;  // global round counter (uniform across blocks)

  for (int s = 0; s < NSTEP; ++s) {
    if (d) {  // frozen: zero logits row; no exchanges (uniform across blocks)
      if (b == 0 && tid < 64) out[512 + s * 64 + tid] = 0.0f;
      continue;
    }

    // ---- round r: h1[b] = relu(dot(concat(v,tgt), W1[:,b]) + b1[b]) ----
    {
      float p = fmaf(v_loc[tid], w1c_s[tid], tgt_s[tid] * w1c_s[tid + 512]);
      p = wredsum(p);
      if (ln == 0) rf8[wv] = p;
      __syncthreads();
      if (tid == 0) {
        float a = b1[b];
        for (int q = 0; q < 8; ++q) a += rf8[q];
        publish(XW(r & (RBUF - 1), b), fmaxf(a, 0.f), (unsigned int)(r + 1));
      }
      if (tid < 256)
        h1_s[tid] = poll_word(XW(r & (RBUF - 1), tid), (unsigned int)(r + 1));
      __syncthreads();
      ++r;
    }

    // ---- replicated L2/L3/softmax (identical in every block) ----
    {
      const int o = tid & 127, q = tid >> 7;
      float a = 0.f;
      const float* w2p = W2 + (q << 6) * 128 + o;
#pragma unroll 8
      for (int i = 0; i < 64; ++i) a = fmaf(h1_s[(q << 6) + i], w2p[i * 128], a);
      redp[tid] = a;
    }
    __syncthreads();
    if (tid < 128) {
      float rr = redp[tid] + redp[tid + 128] + redp[tid + 256] + redp[tid + 384] + b2[tid];
      h2_s[tid] = fmaxf(rr, 0.f);
    }
    __syncthreads();
    {
      const int o = tid & 63, q = tid >> 6;
      float a = 0.f;
      const float* w3p = W3 + (q << 4) * 64 + o;
#pragma unroll
      for (int i = 0; i < 16; ++i) a = fmaf(h2_s[(q << 4) + i], w3p[i * 64], a);
      redp[tid] = a;
    }
    __syncthreads();
    if (tid < 64) {
      float a = b3[tid];
#pragma unroll
      for (int q = 0; q < 8; ++q) a += redp[tid + (q << 6)];
      float lg = a + gum[s * 64 + tid];  // TAU = 1
      float mx = lg;
#pragma unroll
      for (int off = 32; off > 0; off >>= 1) mx = fmaxf(mx, __shfl_xor(mx, off, 64));
      float e = __expf(lg - mx);
      float sm = e;
#pragma unroll
      for (int off = 32; off > 0; off >>= 1) sm += __shfl_xor(sm, off, 64);
      soft_s[tid] = e / sm;
      if (b == 0) out[512 + s * 64 + tid] = a;  // pre-gumbel logits
    }
    __syncthreads();

    // ---- mix 2 rows of A from LDS fp16 ----
    {
      float a0 = 0.f, a1 = 0.f;
#pragma unroll 8
      for (int t = 0; t < 64; ++t) {
        float2 xy = __half22float2(oh[t * 512 + tid]);
        float sv = soft_s[t];
        a0 = fmaf(sv, xy.x, a0);
        a1 = fmaf(sv, xy.y, a1);
      }
      A0_s[tid] = a0; A1_s[tid] = a1;
    }
    __syncthreads();

    // ---- round r: w1 = A v ; publish, gather into w_s ----
    {
      const float* Ar = (tid < 256) ? A0_s : A1_s;
      const int j = tid & 255;
      float p = fmaf(Ar[j], v_loc[j], Ar[j + 256] * v_loc[j + 256]);
      p = wredsum(p);
      if (ln == 0) rf8[wv] = p;
      __syncthreads();
      if (tid == 0) {
        float s0 = rf8[0] + rf8[1] + rf8[2] + rf8[3];
        float s1 = rf8[4] + rf8[5] + rf8[6] + rf8[7];
        acc2[0] = v_loc[(b << 1)] + s0;
        acc2[1] = v_loc[(b << 1) + 1] + s1;
        publish(XW(r & (RBUF - 1), (b << 1)), s0, (unsigned int)(r + 1));
        publish(XW(r & (RBUF - 1), (b << 1) + 1), s1, (unsigned int)(r + 1));
      }
      w_s[tid] = poll_word(XW(r & (RBUF - 1), tid), (unsigned int)(r + 1));
      __syncthreads();
      ++r;
    }

    // ---- rounds: Taylor n = 2..NTAY ; last publishes vnew, gather v_loc ----
    for (int n = 2; n <= NTAY; ++n) {
      const float* Ar = (tid < 256) ? A0_s : A1_s;
      const int j = tid & 255;
      float p = fmaf(Ar[j], w_s[j], Ar[j + 256] * w_s[j + 256]);
      p = wredsum(p);
      if (ln == 0) rf8[wv] = p;
      __syncthreads();
      if (tid == 0) {
        const float inv = 1.0f / (float)n;
        float s0 = (rf8[0] + rf8[1] + rf8[2] + rf8[3]) * inv;
        float s1 = (rf8[4] + rf8[5] + rf8[6] + rf8[7]) * inv;
        acc2[0] += s0; acc2[1] += s1;
        float p0 = (n < NTAY) ? s0 : acc2[0];
        float p1 = (n < NTAY) ? s1 : acc2[1];
        publish(XW(r & (RBUF - 1), (b << 1)), p0, (unsigned int)(r + 1));
        publish(XW(r & (RBUF - 1), (b << 1) + 1), p1, (unsigned int)(r + 1));
      }
      float g = poll_word(XW(r & (RBUF - 1), tid), (unsigned int)(r + 1));
      if (n < NTAY) {
        w_s[tid] = g;
        __syncthreads();
        ++r;
      } else {
        // ---- vnew gathered: carry + done check (identical everywhere) ----
        v_loc[tid] = g;
        float v = g; int ix = tid;
#pragma unroll
        for (int off = 32; off > 0; off >>= 1) {
          float ov = __shfl_xor(v, off, 64); int oi = __shfl_xor(ix, off, 64);
          if (ov > v || (ov == v && oi < ix)) { v = ov; ix = oi; }
        }
        if (ln == 0) { rf8[wv] = v; ri8[wv] = ix; }
        __syncthreads();
        if (tid == 0) {
          float bv = rf8[0]; int bix = ri8[0];
          for (int q = 1; q < 8; ++q)
            if (rf8[q] > bv || (rf8[q] == bv && ri8[q] < bix)) { bv = rf8[q]; bix = ri8[q]; }
          bc[0] = (bix == tgtIdx) ? 1 : 0;
        }
        __syncthreads();
        if (bc[0]) d = 1;
        __syncthreads();
        ++r;
      }
    }
  }

  // ---- epilogue: v_loc holds v_final (frozen at done or vnew_19) ----
  if (b == 0) out[tid] = v_loc[tid];
}

extern "C" void kernel_launch(void* const* d_in, const int* in_sizes, int n_in,
                              void* d_out, int out_size, void* d_ws, size_t ws_size,
                              hipStream_t stream) {
  (void)in_sizes; (void)n_in; (void)out_size; (void)ws_size;
  petri_kernel<<<dim3(NBLK), dim3(NTHR), 0, stream>>>(
      (const float*)d_in[0], (const float*)d_in[1], (const float*)d_in[2],
      (const float*)d_in[3], (const float*)d_in[4], (const float*)d_in[5],
      (const float*)d_in[6], (const float*)d_in[7], (const float*)d_in[8],
      (const float*)d_in[9], (ull*)d_ws, (float*)d_out);
}

// Round 10
// 364.008 us; speedup vs baseline: 3.8169x; 1.1398x over previous
//
#include <hip/hip_runtime.h>
#include <hip/hip_fp16.h>

// Persistent 256-block kernel (1 block/CU forced by ~152 KB LDS).
// Rows 2b,2b+1 of all 64 Omega_t cached ONCE in LDS as fp16 (validated
// R4-R8, absmax 0.0078). NTAY=3 Taylor terms of expm(A)@v.
//
// Exchange (fence-free, R7): relaxed agent-scope 8-byte atomics only.
// R9: TWO floats per word, tag embedded in low-2 mantissa bits of float0
// (one atom -> no ordering needed; perturbation <=3*2^-23 rel). 256 words
// per round, one per 64 B line, 4 rotating buffers (64 KB of d_ws,
// re-poisoned 0xAA each launch; poison low2=2 != tag 0 of rounds 0..3;
// skew induction: publish r+1 strictly after full gather of r -> distance-4
// buffer reuse and period-16 tag reuse are safe).
// W2/W3 in registers; gum/b2/b3 in LDS.
// R9 post-mortem: NaN was gum_s loaded only for tid<512 of 1280 entries ->
// steps >=8 used uninitialized LDS as gumbel noise. R10: grid-stride load.

#define NBLK 256
#define NTHR 512
#define NSTEP 20
#define NTAY 3
#define RBUF 4

typedef unsigned long long ull;

// word i (i<256) of buffer buf: 64 B apart
#define XW(buf, i) (X + ((((buf) << 8) + (i)) << 3))

__device__ __forceinline__ float wredsum(float p) {
#pragma unroll
  for (int off = 32; off > 0; off >>= 1) p += __shfl_xor(p, off, 64);
  return p;
}

__device__ __forceinline__ void publish2(ull* w, float v0, float v1, unsigned int tag2) {
  unsigned int u0 = (__float_as_uint(v0) & ~3u) | tag2;
  ull x = (ull)u0 | ((ull)__float_as_uint(v1) << 32);
  __hip_atomic_store(w, x, __ATOMIC_RELAXED, __HIP_MEMORY_SCOPE_AGENT);
}

__device__ __forceinline__ float2 poll2(ull* w, unsigned int tag2) {
  int it = 0;
  for (;;) {
    ull x = __hip_atomic_load(w, __ATOMIC_RELAXED, __HIP_MEMORY_SCOPE_AGENT);
    if ((unsigned int)(x & 3u) == tag2) {
      float2 r;
      r.x = __uint_as_float((unsigned int)x);
      r.y = __uint_as_float((unsigned int)(x >> 32));
      return r;
    }
    if (it == 0)      __builtin_amdgcn_s_sleep(1);
    else if (it == 1) __builtin_amdgcn_s_sleep(2);
    else              __builtin_amdgcn_s_sleep(4);
    if (it < 2) ++it;
  }
}

__global__ __launch_bounds__(NTHR) void petri_kernel(
    const float* __restrict__ vsrc, const float* __restrict__ vtgt,
    const float* __restrict__ omg,  const float* __restrict__ W1,
    const float* __restrict__ b1,   const float* __restrict__ W2,
    const float* __restrict__ b2,   const float* __restrict__ W3,
    const float* __restrict__ b3,   const float* __restrict__ gum,
    ull* __restrict__ X, float* __restrict__ out) {
  __shared__ __half2 oh[64 * 512];   // 128 KB: {row2b[j], row2b+1[j]} per t
  __shared__ float A0_s[512], A1_s[512];
  __shared__ float v_loc[512], tgt_s[512], w_s[512];
  __shared__ float w1c_s[1024];      // W1 column b (both halves)
  __shared__ float gum_s[NSTEP * 64];
  __shared__ float b2_s[128], b3_s[64];
  __shared__ float soft_s[64], h1_s[256], h2_s[128];
  __shared__ float redp[512];
  __shared__ float rf8[8];
  __shared__ int   ri8[8];
  __shared__ float acc2[2];
  __shared__ int   bc[1];

  const int b = blockIdx.x, tid = threadIdx.x;
  const int wv = tid >> 6, ln = tid & 63;

  v_loc[tid] = vsrc[tid];
  tgt_s[tid] = vtgt[tid];
  w1c_s[tid] = W1[tid * 256 + b];
  w1c_s[tid + 512] = W1[(tid + 512) * 256 + b];
  for (int i = tid; i < NSTEP * 64; i += NTHR) gum_s[i] = gum[i];  // R10 fix
  if (tid >= 512 - 128) {
    int j = tid - (512 - 128);
    b2_s[j] = b2[j];
    if (j < 64) b3_s[j] = b3[j];
  }
  // W2 column slice in registers: thread (o=tid&127,q=tid>>7) holds
  // W2[(q*64+i)*128+o], i=0..63
  float w2r[64];
  {
    const int o = tid & 127, q = tid >> 7;
    const float* p = W2 + ((q << 6) * 128) + o;
#pragma unroll
    for (int i = 0; i < 64; ++i) w2r[i] = p[i * 128];
  }
  // W3 slice: thread (o=tid&63,q=tid>>6) holds W3[(q*16+i)*64+o], i=0..15
  float w3r[16];
  {
    const int o = tid & 63, q = tid >> 6;
    const float* p = W3 + ((q << 4) * 64) + o;
#pragma unroll
    for (int i = 0; i < 16; ++i) w3r[i] = p[i * 64];
  }
  {
    const float* base0 = omg + (b << 10) + tid;  // row 2b of Omega_0, elem tid
#pragma unroll 4
    for (int t = 0; t < 64; ++t) {
      float x0 = base0[t * 262144];
      float x1 = base0[t * 262144 + 512];
      oh[t * 512 + tid] = __floats2half2_rn(x0, x1);
    }
  }
  __syncthreads();

  // target argmax (identical in every block), first-index tie-break
  int tgtIdx;
  {
    float v = tgt_s[tid]; int ix = tid;
#pragma unroll
    for (int off = 32; off > 0; off >>= 1) {
      float ov = __shfl_xor(v, off, 64); int oi = __shfl_xor(ix, off, 64);
      if (ov > v || (ov == v && oi < ix)) { v = ov; ix = oi; }
    }
    if (ln == 0) { rf8[wv] = v; ri8[wv] = ix; }
    __syncthreads();
    if (tid == 0) {
      float bv = rf8[0]; int bix = ri8[0];
      for (int q = 1; q < 8; ++q)
        if (rf8[q] > bv || (rf8[q] == bv && ri8[q] < bix)) { bv = rf8[q]; bix = ri8[q]; }
      bc[0] = bix;
    }
    __syncthreads();
    tgtIdx = bc[0];
    __syncthreads();
  }

  int d = 0;
  int r = 0;  // global round counter (uniform across blocks)

  for (int s = 0; s < NSTEP; ++s) {
    if (d) {  // frozen: zero logits row; no exchanges (uniform across blocks)
      if (b == 0 && tid < 64) out[512 + s * 64 + tid] = 0.0f;
      continue;
    }

    // ---- round: h1[b] = relu(dot(concat(v,tgt), W1[:,b]) + b1[b]) ----
    {
      const int buf = r & (RBUF - 1);
      const unsigned int tg = (unsigned int)((r >> 2) & 3);
      float p = fmaf(v_loc[tid], w1c_s[tid], tgt_s[tid] * w1c_s[tid + 512]);
      p = wredsum(p);
      if (ln == 0) rf8[wv] = p;
      __syncthreads();
      if (tid == 0) {
        float a = b1[b];
        for (int q = 0; q < 8; ++q) a += rf8[q];
        float h = fmaxf(a, 0.f);
        publish2(XW(buf, b), h, h, tg);
      }
      if (tid < 256) h1_s[tid] = poll2(XW(buf, tid), tg).x;
      __syncthreads();
      ++r;
    }

    // ---- replicated L2/L3/softmax (register weights) ----
    {
      const int q = tid >> 7;
      float a = 0.f;
      const float* hp = h1_s + (q << 6);
#pragma unroll
      for (int i = 0; i < 64; ++i) a = fmaf(hp[i], w2r[i], a);
      redp[tid] = a;
    }
    __syncthreads();
    if (tid < 128) {
      float rr = redp[tid] + redp[tid + 128] + redp[tid + 256] + redp[tid + 384] + b2_s[tid];
      h2_s[tid] = fmaxf(rr, 0.f);
    }
    __syncthreads();
    {
      const int q = tid >> 6;
      float a = 0.f;
      const float* hp = h2_s + (q << 4);
#pragma unroll
      for (int i = 0; i < 16; ++i) a = fmaf(hp[i], w3r[i], a);
      redp[tid] = a;
    }
    __syncthreads();
    if (tid < 64) {
      float a = b3_s[tid];
#pragma unroll
      for (int q = 0; q < 8; ++q) a += redp[tid + (q << 6)];
      float lg = a + gum_s[s * 64 + tid];  // TAU = 1
      float mx = lg;
#pragma unroll
      for (int off = 32; off > 0; off >>= 1) mx = fmaxf(mx, __shfl_xor(mx, off, 64));
      float e = __expf(lg - mx);
      float sm = e;
#pragma unroll
      for (int off = 32; off > 0; off >>= 1) sm += __shfl_xor(sm, off, 64);
      soft_s[tid] = e / sm;
      if (b == 0) out[512 + s * 64 + tid] = a;  // pre-gumbel logits
    }
    __syncthreads();

    // ---- mix 2 rows of A from LDS fp16 ----
    {
      float a0 = 0.f, a1 = 0.f;
#pragma unroll 8
      for (int t = 0; t < 64; ++t) {
        float2 xy = __half22float2(oh[t * 512 + tid]);
        float sv = soft_s[t];
        a0 = fmaf(sv, xy.x, a0);
        a1 = fmaf(sv, xy.y, a1);
      }
      A0_s[tid] = a0; A1_s[tid] = a1;
    }
    __syncthreads();

    // ---- round: w1 = A v (packed publish, packed gather) ----
    {
      const int buf = r & (RBUF - 1);
      const unsigned int tg = (unsigned int)((r >> 2) & 3);
      const float* Ar = (tid < 256) ? A0_s : A1_s;
      const int j = tid & 255;
      float p = fmaf(Ar[j], v_loc[j], Ar[j + 256] * v_loc[j + 256]);
      p = wredsum(p);
      if (ln == 0) rf8[wv] = p;
      __syncthreads();
      if (tid == 0) {
        float s0 = rf8[0] + rf8[1] + rf8[2] + rf8[3];
        float s1 = rf8[4] + rf8[5] + rf8[6] + rf8[7];
        acc2[0] = v_loc[(b << 1)] + s0;
        acc2[1] = v_loc[(b << 1) + 1] + s1;
        publish2(XW(buf, b), s0, s1, tg);
      }
      if (tid < 256) {
        float2 g = poll2(XW(buf, tid), tg);
        w_s[(tid << 1)] = g.x;
        w_s[(tid << 1) + 1] = g.y;
      }
      __syncthreads();
      ++r;
    }

    // ---- rounds: Taylor n = 2..NTAY ; last publishes vnew ----
    for (int n = 2; n <= NTAY; ++n) {
      const int buf = r & (RBUF - 1);
      const unsigned int tg = (unsigned int)((r >> 2) & 3);
      const float* Ar = (tid < 256) ? A0_s : A1_s;
      const int j = tid & 255;
      float p = fmaf(Ar[j], w_s[j], Ar[j + 256] * w_s[j + 256]);
      p = wredsum(p);
      if (ln == 0) rf8[wv] = p;
      __syncthreads();
      if (tid == 0) {
        const float inv = 1.0f / (float)n;
        float s0 = (rf8[0] + rf8[1] + rf8[2] + rf8[3]) * inv;
        float s1 = (rf8[4] + rf8[5] + rf8[6] + rf8[7]) * inv;
        acc2[0] += s0; acc2[1] += s1;
        float p0 = (n < NTAY) ? s0 : acc2[0];
        float p1 = (n < NTAY) ? s1 : acc2[1];
        publish2(XW(buf, b), p0, p1, tg);
      }
      if (n < NTAY) {
        if (tid < 256) {
          float2 g = poll2(XW(buf, tid), tg);
          w_s[(tid << 1)] = g.x;
          w_s[(tid << 1) + 1] = g.y;
        }
        __syncthreads();
        ++r;
      } else {
        // ---- gather vnew -> v_loc; carry + done check ----
        if (tid < 256) {
          float2 g = poll2(XW(buf, tid), tg);
          v_loc[(tid << 1)] = g.x;
          v_loc[(tid << 1) + 1] = g.y;
        }
        __syncthreads();
        float v = v_loc[tid]; int ix = tid;
#pragma unroll
        for (int off = 32; off > 0; off >>= 1) {
          float ov = __shfl_xor(v, off, 64); int oi = __shfl_xor(ix, off, 64);
          if (ov > v || (ov == v && oi < ix)) { v = ov; ix = oi; }
        }
        if (ln == 0) { rf8[wv] = v; ri8[wv] = ix; }
        __syncthreads();
        if (tid == 0) {
          float bv = rf8[0]; int bix = ri8[0];
          for (int q = 1; q < 8; ++q)
            if (rf8[q] > bv || (rf8[q] == bv && ri8[q] < bix)) { bv = rf8[q]; bix = ri8[q]; }
          bc[0] = (bix == tgtIdx) ? 1 : 0;
        }
        __syncthreads();
        if (bc[0]) d = 1;
        __syncthreads();
        ++r;
      }
    }
  }

  // ---- epilogue: v_loc holds v_final ----
  if (b == 0) out[tid] = v_loc[tid];
}

extern "C" void kernel_launch(void* const* d_in, const int* in_sizes, int n_in,
                              void* d_out, int out_size, void* d_ws, size_t ws_size,
                              hipStream_t stream) {
  (void)in_sizes; (void)n_in; (void)out_size; (void)ws_size;
  petri_kernel<<<dim3(NBLK), dim3(NTHR), 0, stream>>>(
      (const float*)d_in[0], (const float*)d_in[1], (const float*)d_in[2],
      (const float*)d_in[3], (const float*)d_in[4], (const float*)d_in[5],
      (const float*)d_in[6], (const float*)d_in[7], (const float*)d_in[8],
      (const float*)d_in[9], (ull*)d_ws, (float*)d_out);
}